// Round 14
// baseline (548.063 us; speedup 1.0000x reference)
//
#include <hip/hip_runtime.h>

typedef _Float16 f16x8 __attribute__((ext_vector_type(8)));
typedef _Float16 f16x4 __attribute__((ext_vector_type(4)));
typedef float f32x4 __attribute__((ext_vector_type(4)));

#define N_PIX 4096
#define C_IN  512
#define BN_INV 0.99999500003749969f  // 1/sqrt(1+1e-5)
#define CCH 32  // conv c-chunk (K per LDS stage)

#define GLOAD_LDS16(g, l)                                        \
  __builtin_amdgcn_global_load_lds(                              \
      (const __attribute__((address_space(1))) void*)(g),        \
      (__attribute__((address_space(3))) void*)(l), 16, 0, 0)

__device__ __forceinline__ f32x4 mfma16(f16x8 a, f16x8 b, f32x4 c) {
  return __builtin_amdgcn_mfma_f32_16x16x32_f16(a, b, c, 0, 0, 0);
}
// NT fragment load: row = base_row + (lane&15), 8 contiguous k at k0 + (lane>>4)*8
__device__ __forceinline__ f16x8 ldnt(const _Float16* base, int row, int ld, int k0, int lane) {
  return *(const f16x8*)(base + (size_t)(row + (lane & 15)) * ld + k0 + ((lane >> 4) << 3));
}

// ================= k_pre: xT | f2hx | packw | mean (one dispatch) =================
// blocks [0,8192): xT transpose; [8192,9984): weight casts; [9984,16896): packw;
// [16896,18944): per-(b,c) mean.
__global__ __launch_bounds__(256) void k_pre(const float* __restrict__ x, _Float16* __restrict__ xT,
                                             const float* __restrict__ wa1, _Float16* __restrict__ w1h,
                                             const float* __restrict__ wv, _Float16* __restrict__ wvh,
                                             const float* __restrict__ wq, _Float16* __restrict__ wqh,
                                             const float* __restrict__ wk, _Float16* __restrict__ wkh,
                                             const float* __restrict__ w2, const float* __restrict__ w3,
                                             const float* __restrict__ w4, _Float16* __restrict__ wp,
                                             float* __restrict__ meanv) {
  int bid = blockIdx.x;
  if (bid < 8192) {
    // ---- xT: NCHW fp32 -> [b][pix][c] fp16 ----
    __shared__ float t[32][33];
    int bx = bid & 127, by = (bid >> 7) & 15, b = bid >> 11;
    int p0 = bx * 32, c0 = by * 32;
    int tx = threadIdx.x & 31, ty = threadIdx.x >> 5;  // 32 x 8
    const float* xb = x + ((size_t)b * C_IN + c0) * N_PIX + p0;
    for (int i = 0; i < 32; i += 8) t[ty + i][tx] = xb[(size_t)(ty + i) * N_PIX + tx];
    __syncthreads();
    _Float16* o = xT + ((size_t)b * N_PIX + p0) * C_IN + c0;
    for (int i = 0; i < 32; i += 8) o[(size_t)(ty + i) * C_IN + tx] = (_Float16)t[tx][ty + i];
    return;
  }
  if (bid < 9984) {
    // ---- f2hx: wa1, wv flat; wq, wk first-512-cols strided ----
    int i = (bid - 8192) * 256 + threadIdx.x;
    if (i < 65536) { w1h[i] = (_Float16)wa1[i]; return; }
    i -= 65536;
    if (i < 262144) { wvh[i] = (_Float16)wv[i]; return; }
    i -= 262144;
    if (i < 65536) { int oc = i >> 9, c = i & 511; wqh[i] = (_Float16)wq[oc * 640 + c]; return; }
    i -= 65536;
    if (i < 65536) { int oc = i >> 9, c = i & 511; wkh[i] = (_Float16)wk[oc * 640 + c]; }
    return;
  }
  if (bid < 16896) {
    // ---- packw: [conv][tap][oc][c] fp16 ----
    int idx = (bid - 9984) * 256 + threadIdx.x;  // 3*9*128*512 = 1769472
    int conv = idx / 589824;
    int t1 = idx % 589824;
    int tap = t1 / 65536;
    int t2 = t1 % 65536;
    int oc = t2 / 512, c = t2 % 512;
    const float* w = (conv == 0) ? w2 : (conv == 1) ? w3 : w4;
    wp[idx] = (_Float16)w[(size_t)(oc * 512 + c) * 9 + tap];
    return;
  }
  {
    // ---- mean over pixels ----
    int i = bid - 16896;  // 2048 = 512 c x 4 b
    int c = i & 511, b = i >> 9;
    const float* p = x + ((size_t)b * C_IN + c) * N_PIX;
    float s = 0.f;
    for (int j = threadIdx.x; j < N_PIX; j += 256) s += p[j];
    for (int off = 32; off; off >>= 1) s += __shfl_down(s, off);
    __shared__ float ls[4];
    if ((threadIdx.x & 63) == 0) ls[threadIdx.x >> 6] = s;
    __syncthreads();
    if (threadIdx.x == 0) meanv[(size_t)b * C_IN + c] = (ls[0] + ls[1] + ls[2] + ls[3]) * (1.f / N_PIX);
  }
}

// ================= k_mid: conv | v | p5 (one dispatch) =================
// blocks [0,512): ASPP conv (2 rows x 128 oc); [512,1536): v conv; [1536,1540): p5 fold.
__global__ __launch_bounds__(256, 5) void k_mid(const _Float16* __restrict__ xT, const _Float16* __restrict__ w1h,
                                                const _Float16* __restrict__ wph, const float* __restrict__ bnS,
                                                const float* __restrict__ bnB, _Float16* __restrict__ featT,
                                                const _Float16* __restrict__ wvh, const float* __restrict__ bv,
                                                _Float16* __restrict__ vv, const float* __restrict__ w5,
                                                const float* __restrict__ meanv, const float* __restrict__ wq,
                                                const float* __restrict__ bq, const float* __restrict__ wk,
                                                const float* __restrict__ bk, float* __restrict__ bq2,
                                                float* __restrict__ bk2) {
  __shared__ char smem[6 * 76 * CCH * 2];  // 29184 B (conv Ap; p5 reuses head)
  int bid0 = blockIdx.x;
  if (bid0 < 512) {
    // ---- unified ASPP conv: LDS-staged implicit GEMM, 2 output rows per block ----
    // Fill loops literal-unrolled; tap weights software-pipelined (prefetch tap+1).
    _Float16* Ap = (_Float16*)smem;
    int y0 = (bid0 & 31) * 2;
    int tb = bid0 >> 5;
    int task = tb >> 2, b = tb & 3;
    int tid = threadIdx.x, wid = tid >> 6, lane = tid & 63;
    int dil = (task == 0) ? 0 : (task == 1) ? 2 : (task == 2) ? 3 : 6;
    int ntap = task ? 9 : 1;
    const _Float16* wt0 = task ? wph + (size_t)(task - 1) * 9 * 128 * C_IN : w1h;
    f32x4 acc[8][2] = {};

    for (int cc = 0; cc < C_IN / CCH; ++cc) {
      int c0 = cc * CCH;
      __syncthreads();  // previous chunk's compute done reading LDS
      // tap-0 weights for this chunk (overlaps staging below)
      f16x8 wf0 = ldnt(wt0, wid * 32, C_IN, c0, lane);
      f16x8 wf1 = ldnt(wt0, wid * 32 + 16, C_IN, c0, lane);
      if (dil) {
        int nz = 6 * 2 * dil * (CCH / 8);
        for (int i = tid; i < nz; i += 256) {
          int cv = (i & (CCH / 8 - 1)) * 8;
          int t2 = i / (CCH / 8);
          int colh = t2 % (2 * dil);
          int rband = t2 / (2 * dil);
          int col = (colh < dil) ? colh : 64 + colh;
          int ba = (((rband * 76 + col) * CCH + cv) * 2) ^ ((col & 7) << 4);
          *(f16x8*)((char*)Ap + ba) = (f16x8){};
        }
      }
      // fill row-bands: literal trip counts so all global loads issue together
      auto fill1 = [&](int i) {
        int cv = (i & (CCH / 8 - 1)) * 8;
        int t2 = i / (CCH / 8);
        int px = t2 & 63;
        int rband = t2 >> 6;
        int ry = y0 + (rband & 1) + ((rband >> 1) - 1) * dil;
        f16x8 v = {};
        if ((unsigned)ry < 64u)
          v = *(const f16x8*)(xT + ((size_t)b * N_PIX + ry * 64 + px) * C_IN + c0 + cv);
        int col = dil + px;
        int ba = (((rband * 76 + col) * CCH + cv) * 2) ^ ((col & 7) << 4);
        *(f16x8*)((char*)Ap + ba) = v;
      };
      if (task) {
#pragma unroll
        for (int j = 0; j < 6; ++j) fill1(tid + j * 256);  // 6 bands
      } else {
#pragma unroll
        for (int j = 0; j < 2; ++j) fill1(tid + j * 256);  // 2 bands
      }
      __syncthreads();
      for (int tap = 0; tap < ntap; ++tap) {
        // prefetch next tap's weights; MFMAs below cover the latency
        f16x8 nf0 = wf0, nf1 = wf1;
        if (tap + 1 < ntap) {
          const _Float16* wn = wt0 + (size_t)(tap + 1) * 128 * C_IN;
          nf0 = ldnt(wn, wid * 32, C_IN, c0, lane);
          nf1 = ldnt(wn, wid * 32 + 16, C_IN, c0, lane);
        }
        int band = tap / 3;
        int dx = (tap % 3 - 1) * dil;
#pragma unroll
        for (int m = 0; m < 8; ++m) {
          int rband = band * 2 + (m >> 2);
          int col = dil + dx + (m & 3) * 16 + (lane & 15);
          int ch = (lane >> 4) << 3;
          int ba = (((rband * 76 + col) * CCH + ch) * 2) ^ ((col & 7) << 4);
          f16x8 af = *(const f16x8*)((char*)Ap + ba);
          acc[m][0] = mfma16(af, wf0, acc[m][0]);
          acc[m][1] = mfma16(af, wf1, acc[m][1]);
        }
        wf0 = nf0;
        wf1 = nf1;
      }
    }
    int brOff = task * 128;
    _Float16* F = featT + (size_t)b * N_PIX * 512;
#pragma unroll
    for (int n = 0; n < 2; ++n) {
      int oc = wid * 32 + n * 16 + (lane & 15);
      float inv = bnS[brOff + oc] * BN_INV, bs = bnB[brOff + oc];
#pragma unroll
      for (int m = 0; m < 8; ++m) {
#pragma unroll
        for (int r = 0; r < 4; ++r) {
          int pix = (y0 + (m >> 2)) * 64 + (m & 3) * 16 + ((lane >> 4) << 2) + r;
          F[(size_t)pix * 512 + brOff + oc] = (_Float16)fmaxf(acc[m][n][r] * inv + bs, 0.f);
        }
      }
    }
    return;
  }
  if (bid0 < 1536) {
    // ---- v: 1x1 conv 512->512 + bias -> [b][c][pix], XCD swizzle ----
    int bid = bid0 - 512;
    int swz = (bid & 7) * 128 + (bid >> 3);
    int oc0 = (swz & 7) * 64;
    int p0 = ((swz >> 3) & 31) * 128;
    int b = swz >> 8;
    int tid = threadIdx.x, wid = tid >> 6, lane = tid & 63;
    const _Float16* Bm = xT + (size_t)b * N_PIX * C_IN;
    int or0 = oc0 + wid * 16;
    f32x4 acc[8] = {};
    for (int kk = 0; kk < 16; ++kk) {
      f16x8 af = ldnt(wvh, or0, C_IN, kk * 32, lane);
#pragma unroll
      for (int nn = 0; nn < 8; ++nn) {
        f16x8 bf = ldnt(Bm, p0 + nn * 16, C_IN, kk * 32, lane);
        acc[nn] = mfma16(af, bf, acc[nn]);
      }
    }
    _Float16* V = vv + (size_t)b * C_IN * N_PIX;
#pragma unroll
    for (int r = 0; r < 4; ++r) {
      int oc = or0 + ((lane >> 4) << 2) + r;
      float bb = bv[oc];
#pragma unroll
      for (int nn = 0; nn < 8; ++nn) {
        int pix = p0 + nn * 16 + (lane & 15);
        V[(size_t)oc * N_PIX + pix] = (_Float16)(acc[nn][r] + bb);
      }
    }
    return;
  }
  {
    // ---- p5 fold: p5 = relu(bn(w5 . mean)); bq2/bk2 = bias + W[:,512:640] . p5 ----
    float* p5s = (float*)smem;
    int b = bid0 - 1536;
    int oc = threadIdx.x;  // use threads 0-127
    if (oc < 128) {
      const float* m = meanv + (size_t)b * C_IN;
      const float* w = w5 + (size_t)oc * C_IN;
      float s = 0.f;
      for (int c = 0; c < C_IN; ++c) s += w[c] * m[c];
      p5s[oc] = fmaxf(s * bnS[4 * 128 + oc] * BN_INV + bnB[4 * 128 + oc], 0.f);
    }
    __syncthreads();
    if (oc < 128) {
      float aq = bq[oc], ak = bk[oc];
      for (int c = 0; c < 128; ++c) {
        float pv = p5s[c];
        aq += wq[oc * 640 + 512 + c] * pv;
        ak += wk[oc * 640 + 512 + c] * pv;
      }
      bq2[b * 128 + oc] = aq;
      bk2[b * 128 + oc] = ak;
    }
  }
}

// ---------- q & k: 1x1 conv 512->128 + per-b bias (b5 folded) -> [b][pix][128] fp16 ----------
__global__ __launch_bounds__(256) void k_qk(const _Float16* __restrict__ featT, const _Float16* __restrict__ wqh,
                                            const _Float16* __restrict__ wkh, const float* __restrict__ bq2,
                                            const float* __restrict__ bk2, _Float16* __restrict__ qT,
                                            _Float16* __restrict__ kT) {
  int b = blockIdx.z, which = blockIdx.y, p0 = blockIdx.x * 32;
  const _Float16* wh = which ? wkh : wqh;
  const float* bias = (which ? bk2 : bq2) + b * 128;
  _Float16* oT = which ? kT : qT;
  int tid = threadIdx.x, wid = tid >> 6, lane = tid & 63;
  int pw = wid & 1, ocq = wid >> 1;
  const _Float16* A = featT + (size_t)b * N_PIX * 512;
  int pr = p0 + pw * 16;
  f32x4 acc[4] = {};
  for (int kk = 0; kk < 16; ++kk) {
    f16x8 af = ldnt(A, pr, 512, kk * 32, lane);
#pragma unroll
    for (int nn = 0; nn < 4; ++nn) {
      f16x8 bf = ldnt(wh, ocq * 64 + nn * 16, 512, kk * 32, lane);
      acc[nn] = mfma16(af, bf, acc[nn]);
    }
  }
  _Float16* O = oT + (size_t)b * N_PIX * 128;
#pragma unroll
  for (int nn = 0; nn < 4; ++nn) {
    int oc = ocq * 64 + nn * 16 + (lane & 15);
    float bb = bias[oc];
#pragma unroll
    for (int r = 0; r < 4; ++r) {
      int pix = pr + ((lane >> 4) << 2) + r;
      O[(size_t)pix * 128 + oc] = (_Float16)(acc[nn][r] + bb);
    }
  }
}

// ---------- one-pass fused attention, producer/consumer, 12 waves, XCD swizzle ----------
// Waves 0-3: QK^T + online softmax. Waves 4-11: K staging + PV (64 c each).
__global__ __launch_bounds__(768, 3) void k_attn(const _Float16* __restrict__ qT, const _Float16* __restrict__ kT,
                                                 const _Float16* __restrict__ vv, const float* __restrict__ x,
                                                 const float* __restrict__ gamma, float* __restrict__ out) {
  __shared__ _Float16 Kb[2][128 * 128];  // 2 x 32KB, row 256B, swizzled by (m&7)<<4
  __shared__ _Float16 P[2][64 * 128];    // 2 x 16KB, row 256B, swizzled by (n&7)<<4
  __shared__ float fbuf[2][64];          // per-n rescale factor, per P buffer
  __shared__ float sbuf[64];             // final sums
  int bid = blockIdx.x;
  int swz = (bid & 7) * 32 + (bid >> 3);
  int n0 = (swz & 63) * 64;
  int b = swz >> 6;
  int tid = threadIdx.x, wid = tid >> 6, lane = tid & 63;
  const _Float16* Q = qT + (size_t)b * N_PIX * 128;
  const _Float16* K = kT + (size_t)b * N_PIX * 128;
  const _Float16* V = vv + (size_t)b * C_IN * N_PIX;
  float g = gamma[0];
  f16x8 qf[4];
  int n_local = (wid & 3) * 16 + (lane & 15);
  if (wid < 4) {
#pragma unroll
    for (int kk = 0; kk < 4; ++kk) qf[kk] = ldnt(Q, n0 + wid * 16, 128, kk * 32, lane);
  }
  float m_run = -3.4e38f, sm = 0.f;
  f32x4 acc[4][4];  // consumer: [cc][nn], 64 VGPR
#pragma unroll
  for (int cc = 0; cc < 4; ++cc)
#pragma unroll
    for (int nn = 0; nn < 4; ++nn) acc[cc][nn] = (f32x4){};

  auto stageK = [&](int it, int buf) {  // waves 4-11 (consumers), 16 rows each
    const _Float16* src = K + (size_t)it * 128 * 128;
    int w8 = wid - 4;
    int cs = (lane & 15) << 4;
#pragma unroll
    for (int i = 0; i < 4; ++i) {
      int rr = w8 * 16 + i * 4 + (lane >> 4);
      const char* gp = (const char*)(src + (size_t)rr * 128) + (cs ^ ((rr & 7) << 4));
      char* lp = (char*)&Kb[buf][0] + (size_t)(w8 * 16 + i * 4) * 256;
      GLOAD_LDS16(gp, lp);
    }
  };

  // producer: S^T for 16 n x 128 m from Kb[it&1], online max/sum, P/fbuf[it&1]
  auto phaseA = [&](int it) {
    int buf = it & 1;
    const char* kb = (const char*)&Kb[buf][0];
    f32x4 s8[8];
#pragma unroll
    for (int mm = 0; mm < 8; ++mm) {
      int row = mm * 16 + (lane & 15);
      int kboff = (lane >> 4) << 4;
      f32x4 s = {};
#pragma unroll
      for (int kk = 0; kk < 4; ++kk) {
        f16x8 kf = *(const f16x8*)(kb + (size_t)row * 256 + ((kk * 64 + kboff) ^ ((row & 7) << 4)));
        s = mfma16(kf, qf[kk], s);  // S^T: col=n, rows=m
      }
      s8[mm] = s;
    }
    float tmx = s8[0][0];
#pragma unroll
    for (int mm = 0; mm < 8; ++mm)
      tmx = fmaxf(tmx, fmaxf(fmaxf(s8[mm][0], s8[mm][1]), fmaxf(s8[mm][2], s8[mm][3])));
    tmx = fmaxf(tmx, __shfl_xor(tmx, 16));
    tmx = fmaxf(tmx, __shfl_xor(tmx, 32));  // per-n slab max
    float f = 1.f;
    if (tmx > m_run + 8.f) {  // defer-max: tolerate P up to e^8
      f = __expf(m_run - tmx);
      m_run = tmx;
    }
    sm *= f;
    if (lane < 16) fbuf[buf][n_local] = f;
#pragma unroll
    for (int mm = 0; mm < 8; ++mm) {
      f16x4 pv;
#pragma unroll
      for (int r = 0; r < 4; ++r) {
        float p = __expf(s8[mm][r] - m_run);
        sm += p;
        pv[r] = (_Float16)p;
      }
      int m_local = mm * 16 + ((lane >> 4) << 2);
      *(f16x4*)((char*)&P[buf][0] + (size_t)n_local * 256 + ((m_local * 2) ^ ((n_local & 7) << 4))) = pv;
    }
  };

  // consumer: PV for 64 c (wid-4) from P[it&1]
  auto phaseB = [&](int it) {
    int buf = it & 1;
    int c0 = (wid - 4) * 64;
    float f[4];
#pragma unroll
    for (int nn = 0; nn < 4; ++nn) f[nn] = fbuf[buf][nn * 16 + (lane & 15)];
    bool need = (f[0] != 1.f) | (f[1] != 1.f) | (f[2] != 1.f) | (f[3] != 1.f);
    if (__any(need)) {
#pragma unroll
      for (int cc = 0; cc < 4; ++cc)
#pragma unroll
        for (int nn = 0; nn < 4; ++nn) acc[cc][nn] = acc[cc][nn] * f[nn];
    }
#pragma unroll
    for (int k2 = 0; k2 < 4; ++k2) {
      f16x8 pb[4];
#pragma unroll
      for (int nn = 0; nn < 4; ++nn) {
        int n = nn * 16 + (lane & 15);
        int mbyte = k2 * 64 + ((lane >> 4) << 4);
        pb[nn] = *(const f16x8*)((char*)&P[buf][0] + (size_t)n * 256 + (mbyte ^ ((n & 7) << 4)));
      }
      __builtin_amdgcn_s_setprio(1);
#pragma unroll
      for (int cc = 0; cc < 4; ++cc) {
        f16x8 af = ldnt(V, c0 + cc * 16, N_PIX, it * 128 + k2 * 32, lane);
#pragma unroll
        for (int nn = 0; nn < 4; ++nn) acc[cc][nn] = mfma16(af, pb[nn], acc[cc][nn]);
      }
      __builtin_amdgcn_s_setprio(0);
    }
  };

  // prologue: consumers stage tiles 0 and 1; producers compute P for tile 0
  if (wid >= 4) {
    stageK(0, 0);
    stageK(1, 1);
  }
  __syncthreads();
  if (wid < 4) phaseA(0);
  __syncthreads();
  // steady state: ONE barrier per iteration
  for (int it = 0; it < 32; ++it) {
    if (wid < 4) {
      if (it < 31) phaseA(it + 1);
    } else {
      if (it < 30) stageK(it + 2, it & 1);  // Kb[it&1] last read in interval it-1
      phaseB(it);
    }
    __syncthreads();
  }

  // epilogue: producers publish per-n total sums; consumers write out
  if (wid < 4) {
    float st = sm;
    st += __shfl_xor(st, 16);
    st += __shfl_xor(st, 32);
    if (lane < 16) sbuf[n_local] = st;
  }
  __syncthreads();
  if (wid >= 4) {
    int c0 = (wid - 4) * 64;
    float inv_s[4];
#pragma unroll
    for (int nn = 0; nn < 4; ++nn) inv_s[nn] = 1.f / sbuf[nn * 16 + (lane & 15)];
#pragma unroll
    for (int cc = 0; cc < 4; ++cc) {
#pragma unroll
      for (int r = 0; r < 4; ++r) {
        int oc = c0 + cc * 16 + ((lane >> 4) << 2) + r;
#pragma unroll
        for (int nn = 0; nn < 4; ++nn) {
          int pix = n0 + nn * 16 + (lane & 15);
          size_t idx = ((size_t)(b * C_IN + oc)) * N_PIX + pix;
          out[idx] = fmaf(g * inv_s[nn], acc[cc][nn][r], x[idx]);
        }
      }
    }
  }
}

extern "C" void kernel_launch(void* const* d_in, const int* in_sizes, int n_in,
                              void* d_out, int out_size, void* d_ws, size_t ws_size,
                              hipStream_t stream) {
  const float* x = (const float*)d_in[0];
  const float* wa1 = (const float*)d_in[1];
  const float* wa2 = (const float*)d_in[2];
  const float* wa3 = (const float*)d_in[3];
  const float* wa4 = (const float*)d_in[4];
  const float* wa5 = (const float*)d_in[5];
  const float* bnS = (const float*)d_in[6];
  const float* bnB = (const float*)d_in[7];
  const float* wq = (const float*)d_in[8];
  const float* bq = (const float*)d_in[9];
  const float* wk = (const float*)d_in[10];
  const float* bk = (const float*)d_in[11];
  const float* wv = (const float*)d_in[12];
  const float* bv = (const float*)d_in[13];
  const float* gamma = (const float*)d_in[14];

  char* ws = (char*)d_ws;
  size_t off = 0;
  auto alloc = [&](size_t bytes) -> char* {
    char* p = ws + off;
    off = (off + bytes + 255) & ~(size_t)255;
    return p;
  };
  _Float16* xT = (_Float16*)alloc((size_t)4 * 4096 * 512 * 2);
  _Float16* featT = (_Float16*)alloc((size_t)4 * 4096 * 512 * 2);
  _Float16* qT = (_Float16*)alloc((size_t)4 * 4096 * 128 * 2);
  _Float16* kT = (_Float16*)alloc((size_t)4 * 4096 * 128 * 2);
  _Float16* vvp = (_Float16*)alloc((size_t)4 * 512 * 4096 * 2);
  _Float16* w1h = (_Float16*)alloc((size_t)128 * 512 * 2);
  _Float16* wph = (_Float16*)alloc((size_t)3 * 9 * 128 * 512 * 2);
  _Float16* wqh = (_Float16*)alloc((size_t)128 * 512 * 2);
  _Float16* wkh = (_Float16*)alloc((size_t)128 * 512 * 2);
  _Float16* wvh = (_Float16*)alloc((size_t)512 * 512 * 2);
  float* meanv = (float*)alloc((size_t)4 * 512 * 4);
  float* bq2 = (float*)alloc((size_t)4 * 128 * 4);
  float* bk2 = (float*)alloc((size_t)4 * 128 * 4);
  if (off > ws_size) return;  // workspace too small -> fail loudly via wrong output

  float* out = (float*)d_out;

  // 1) preprocessing (xT | weight casts | packw | mean)
  hipLaunchKernelGGL(k_pre, dim3(18944), dim3(256), 0, stream, x, xT, wa1, w1h, wv, wvh, wq, wqh, wk, wkh,
                     wa2, wa3, wa4, wph, meanv);
  // 2) conv | v | p5 (co-scheduled)
  hipLaunchKernelGGL(k_mid, dim3(1540), dim3(256), 0, stream, xT, w1h, wph, bnS, bnB, featT, wvh, bv, vvp,
                     wa5, meanv, wq, bq, wk, bk, bq2, bk2);
  // 3) q, k
  hipLaunchKernelGGL(k_qk, dim3(128, 2, 4), dim3(256), 0, stream, featT, wqh, wkh, bq2, bk2, qT, kT);
  // 4) one-pass attention (producer/consumer, 12 waves)
  hipLaunchKernelGGL(k_attn, dim3(256), dim3(768), 0, stream, qT, kT, vvp, x, gamma, out);
}

// Round 15
// 377.846 us; speedup vs baseline: 1.4505x; 1.4505x over previous
//
#include <hip/hip_runtime.h>

typedef _Float16 f16x8 __attribute__((ext_vector_type(8)));
typedef _Float16 f16x4 __attribute__((ext_vector_type(4)));
typedef float f32x4 __attribute__((ext_vector_type(4)));

#define N_PIX 4096
#define C_IN  512
#define BN_INV 0.99999500003749969f  // 1/sqrt(1+1e-5)
#define CCH 32  // conv c-chunk (K per LDS stage)

#define GLOAD_LDS16(g, l)                                        \
  __builtin_amdgcn_global_load_lds(                              \
      (const __attribute__((address_space(1))) void*)(g),        \
      (__attribute__((address_space(3))) void*)(l), 16, 0, 0)

__device__ __forceinline__ f32x4 mfma16(f16x8 a, f16x8 b, f32x4 c) {
  return __builtin_amdgcn_mfma_f32_16x16x32_f16(a, b, c, 0, 0, 0);
}
// NT fragment load: row = base_row + (lane&15), 8 contiguous k at k0 + (lane>>4)*8
__device__ __forceinline__ f16x8 ldnt(const _Float16* base, int row, int ld, int k0, int lane) {
  return *(const f16x8*)(base + (size_t)(row + (lane & 15)) * ld + k0 + ((lane >> 4) << 3));
}

// ================= k_pre: xT | f2hx | packw | mean (one dispatch) =================
// blocks [0,8192): xT transpose; [8192,9984): weight casts; [9984,16896): packw;
// [16896,18944): per-(b,c) mean.
__global__ __launch_bounds__(256) void k_pre(const float* __restrict__ x, _Float16* __restrict__ xT,
                                             const float* __restrict__ wa1, _Float16* __restrict__ w1h,
                                             const float* __restrict__ wv, _Float16* __restrict__ wvh,
                                             const float* __restrict__ wq, _Float16* __restrict__ wqh,
                                             const float* __restrict__ wk, _Float16* __restrict__ wkh,
                                             const float* __restrict__ w2, const float* __restrict__ w3,
                                             const float* __restrict__ w4, _Float16* __restrict__ wp,
                                             float* __restrict__ meanv) {
  int bid = blockIdx.x;
  if (bid < 8192) {
    // ---- xT: NCHW fp32 -> [b][pix][c] fp16 ----
    __shared__ float t[32][33];
    int bx = bid & 127, by = (bid >> 7) & 15, b = bid >> 11;
    int p0 = bx * 32, c0 = by * 32;
    int tx = threadIdx.x & 31, ty = threadIdx.x >> 5;  // 32 x 8
    const float* xb = x + ((size_t)b * C_IN + c0) * N_PIX + p0;
    for (int i = 0; i < 32; i += 8) t[ty + i][tx] = xb[(size_t)(ty + i) * N_PIX + tx];
    __syncthreads();
    _Float16* o = xT + ((size_t)b * N_PIX + p0) * C_IN + c0;
    for (int i = 0; i < 32; i += 8) o[(size_t)(ty + i) * C_IN + tx] = (_Float16)t[tx][ty + i];
    return;
  }
  if (bid < 9984) {
    // ---- f2hx: wa1, wv flat; wq, wk first-512-cols strided ----
    int i = (bid - 8192) * 256 + threadIdx.x;
    if (i < 65536) { w1h[i] = (_Float16)wa1[i]; return; }
    i -= 65536;
    if (i < 262144) { wvh[i] = (_Float16)wv[i]; return; }
    i -= 262144;
    if (i < 65536) { int oc = i >> 9, c = i & 511; wqh[i] = (_Float16)wq[oc * 640 + c]; return; }
    i -= 65536;
    if (i < 65536) { int oc = i >> 9, c = i & 511; wkh[i] = (_Float16)wk[oc * 640 + c]; }
    return;
  }
  if (bid < 16896) {
    // ---- packw: [conv][tap][oc][c] fp16 ----
    int idx = (bid - 9984) * 256 + threadIdx.x;  // 3*9*128*512 = 1769472
    int conv = idx / 589824;
    int t1 = idx % 589824;
    int tap = t1 / 65536;
    int t2 = t1 % 65536;
    int oc = t2 / 512, c = t2 % 512;
    const float* w = (conv == 0) ? w2 : (conv == 1) ? w3 : w4;
    wp[idx] = (_Float16)w[(size_t)(oc * 512 + c) * 9 + tap];
    return;
  }
  {
    // ---- mean over pixels ----
    int i = bid - 16896;  // 2048 = 512 c x 4 b
    int c = i & 511, b = i >> 9;
    const float* p = x + ((size_t)b * C_IN + c) * N_PIX;
    float s = 0.f;
    for (int j = threadIdx.x; j < N_PIX; j += 256) s += p[j];
    for (int off = 32; off; off >>= 1) s += __shfl_down(s, off);
    __shared__ float ls[4];
    if ((threadIdx.x & 63) == 0) ls[threadIdx.x >> 6] = s;
    __syncthreads();
    if (threadIdx.x == 0) meanv[(size_t)b * C_IN + c] = (ls[0] + ls[1] + ls[2] + ls[3]) * (1.f / N_PIX);
  }
}

// ================= k_mid: conv | v | p5 (one dispatch) =================
// blocks [0,512): ASPP conv (2 rows x 128 oc); [512,1536): v conv; [1536,1540): p5 fold.
__global__ __launch_bounds__(256, 4) void k_mid(const _Float16* __restrict__ xT, const _Float16* __restrict__ w1h,
                                                const _Float16* __restrict__ wph, const float* __restrict__ bnS,
                                                const float* __restrict__ bnB, _Float16* __restrict__ featT,
                                                const _Float16* __restrict__ wvh, const float* __restrict__ bv,
                                                _Float16* __restrict__ vv, const float* __restrict__ w5,
                                                const float* __restrict__ meanv, const float* __restrict__ wq,
                                                const float* __restrict__ bq, const float* __restrict__ wk,
                                                const float* __restrict__ bk, float* __restrict__ bq2,
                                                float* __restrict__ bk2) {
  __shared__ char smem[6 * 76 * CCH * 2];  // 29184 B (conv Ap; p5 reuses head)
  int bid0 = blockIdx.x;
  if (bid0 < 512) {
    // ---- unified ASPP conv: LDS-staged implicit GEMM, 2 output rows per block ----
    // Fill loops literal-unrolled; tap weights software-pipelined (prefetch tap+1).
    _Float16* Ap = (_Float16*)smem;
    int y0 = (bid0 & 31) * 2;
    int tb = bid0 >> 5;
    int task = tb >> 2, b = tb & 3;
    int tid = threadIdx.x, wid = tid >> 6, lane = tid & 63;
    int dil = (task == 0) ? 0 : (task == 1) ? 2 : (task == 2) ? 3 : 6;
    int ntap = task ? 9 : 1;
    const _Float16* wt0 = task ? wph + (size_t)(task - 1) * 9 * 128 * C_IN : w1h;
    f32x4 acc[8][2] = {};

    for (int cc = 0; cc < C_IN / CCH; ++cc) {
      int c0 = cc * CCH;
      __syncthreads();  // previous chunk's compute done reading LDS
      // tap-0 weights for this chunk (overlaps staging below)
      f16x8 wf0 = ldnt(wt0, wid * 32, C_IN, c0, lane);
      f16x8 wf1 = ldnt(wt0, wid * 32 + 16, C_IN, c0, lane);
      if (dil) {
        int nz = 6 * 2 * dil * (CCH / 8);
        for (int i = tid; i < nz; i += 256) {
          int cv = (i & (CCH / 8 - 1)) * 8;
          int t2 = i / (CCH / 8);
          int colh = t2 % (2 * dil);
          int rband = t2 / (2 * dil);
          int col = (colh < dil) ? colh : 64 + colh;
          int ba = (((rband * 76 + col) * CCH + cv) * 2) ^ ((col & 7) << 4);
          *(f16x8*)((char*)Ap + ba) = (f16x8){};
        }
      }
      // fill row-bands: literal trip counts so all global loads issue together
      auto fill1 = [&](int i) {
        int cv = (i & (CCH / 8 - 1)) * 8;
        int t2 = i / (CCH / 8);
        int px = t2 & 63;
        int rband = t2 >> 6;
        int ry = y0 + (rband & 1) + ((rband >> 1) - 1) * dil;
        f16x8 v = {};
        if ((unsigned)ry < 64u)
          v = *(const f16x8*)(xT + ((size_t)b * N_PIX + ry * 64 + px) * C_IN + c0 + cv);
        int col = dil + px;
        int ba = (((rband * 76 + col) * CCH + cv) * 2) ^ ((col & 7) << 4);
        *(f16x8*)((char*)Ap + ba) = v;
      };
      if (task) {
#pragma unroll
        for (int j = 0; j < 6; ++j) fill1(tid + j * 256);  // 6 bands
      } else {
#pragma unroll
        for (int j = 0; j < 2; ++j) fill1(tid + j * 256);  // 2 bands
      }
      __syncthreads();
      for (int tap = 0; tap < ntap; ++tap) {
        // prefetch next tap's weights; MFMAs below cover the latency
        f16x8 nf0 = wf0, nf1 = wf1;
        if (tap + 1 < ntap) {
          const _Float16* wn = wt0 + (size_t)(tap + 1) * 128 * C_IN;
          nf0 = ldnt(wn, wid * 32, C_IN, c0, lane);
          nf1 = ldnt(wn, wid * 32 + 16, C_IN, c0, lane);
        }
        int band = tap / 3;
        int dx = (tap % 3 - 1) * dil;
#pragma unroll
        for (int m = 0; m < 8; ++m) {
          int rband = band * 2 + (m >> 2);
          int col = dil + dx + (m & 3) * 16 + (lane & 15);
          int ch = (lane >> 4) << 3;
          int ba = (((rband * 76 + col) * CCH + ch) * 2) ^ ((col & 7) << 4);
          f16x8 af = *(const f16x8*)((char*)Ap + ba);
          acc[m][0] = mfma16(af, wf0, acc[m][0]);
          acc[m][1] = mfma16(af, wf1, acc[m][1]);
        }
        wf0 = nf0;
        wf1 = nf1;
      }
    }
    int brOff = task * 128;
    _Float16* F = featT + (size_t)b * N_PIX * 512;
#pragma unroll
    for (int n = 0; n < 2; ++n) {
      int oc = wid * 32 + n * 16 + (lane & 15);
      float inv = bnS[brOff + oc] * BN_INV, bs = bnB[brOff + oc];
#pragma unroll
      for (int m = 0; m < 8; ++m) {
#pragma unroll
        for (int r = 0; r < 4; ++r) {
          int pix = (y0 + (m >> 2)) * 64 + (m & 3) * 16 + ((lane >> 4) << 2) + r;
          F[(size_t)pix * 512 + brOff + oc] = (_Float16)fmaxf(acc[m][n][r] * inv + bs, 0.f);
        }
      }
    }
    return;
  }
  if (bid0 < 1536) {
    // ---- v: 1x1 conv 512->512 + bias -> [b][c][pix], XCD swizzle ----
    int bid = bid0 - 512;
    int swz = (bid & 7) * 128 + (bid >> 3);
    int oc0 = (swz & 7) * 64;
    int p0 = ((swz >> 3) & 31) * 128;
    int b = swz >> 8;
    int tid = threadIdx.x, wid = tid >> 6, lane = tid & 63;
    const _Float16* Bm = xT + (size_t)b * N_PIX * C_IN;
    int or0 = oc0 + wid * 16;
    f32x4 acc[8] = {};
    for (int kk = 0; kk < 16; ++kk) {
      f16x8 af = ldnt(wvh, or0, C_IN, kk * 32, lane);
#pragma unroll
      for (int nn = 0; nn < 8; ++nn) {
        f16x8 bf = ldnt(Bm, p0 + nn * 16, C_IN, kk * 32, lane);
        acc[nn] = mfma16(af, bf, acc[nn]);
      }
    }
    _Float16* V = vv + (size_t)b * C_IN * N_PIX;
#pragma unroll
    for (int r = 0; r < 4; ++r) {
      int oc = or0 + ((lane >> 4) << 2) + r;
      float bb = bv[oc];
#pragma unroll
      for (int nn = 0; nn < 8; ++nn) {
        int pix = p0 + nn * 16 + (lane & 15);
        V[(size_t)oc * N_PIX + pix] = (_Float16)(acc[nn][r] + bb);
      }
    }
    return;
  }
  {
    // ---- p5 fold: p5 = relu(bn(w5 . mean)); bq2/bk2 = bias + W[:,512:640] . p5 ----
    float* p5s = (float*)smem;
    int b = bid0 - 1536;
    int oc = threadIdx.x;  // use threads 0-127
    if (oc < 128) {
      const float* m = meanv + (size_t)b * C_IN;
      const float* w = w5 + (size_t)oc * C_IN;
      float s = 0.f;
      for (int c = 0; c < C_IN; ++c) s += w[c] * m[c];
      p5s[oc] = fmaxf(s * bnS[4 * 128 + oc] * BN_INV + bnB[4 * 128 + oc], 0.f);
    }
    __syncthreads();
    if (oc < 128) {
      float aq = bq[oc], ak = bk[oc];
      for (int c = 0; c < 128; ++c) {
        float pv = p5s[c];
        aq += wq[oc * 640 + 512 + c] * pv;
        ak += wk[oc * 640 + 512 + c] * pv;
      }
      bq2[b * 128 + oc] = aq;
      bk2[b * 128 + oc] = ak;
    }
  }
}

// ---------- q & k: 1x1 conv 512->128 + per-b bias (b5 folded) -> [b][pix][128] fp16 ----------
__global__ __launch_bounds__(256) void k_qk(const _Float16* __restrict__ featT, const _Float16* __restrict__ wqh,
                                            const _Float16* __restrict__ wkh, const float* __restrict__ bq2,
                                            const float* __restrict__ bk2, _Float16* __restrict__ qT,
                                            _Float16* __restrict__ kT) {
  int b = blockIdx.z, which = blockIdx.y, p0 = blockIdx.x * 32;
  const _Float16* wh = which ? wkh : wqh;
  const float* bias = (which ? bk2 : bq2) + b * 128;
  _Float16* oT = which ? kT : qT;
  int tid = threadIdx.x, wid = tid >> 6, lane = tid & 63;
  int pw = wid & 1, ocq = wid >> 1;
  const _Float16* A = featT + (size_t)b * N_PIX * 512;
  int pr = p0 + pw * 16;
  f32x4 acc[4] = {};
  for (int kk = 0; kk < 16; ++kk) {
    f16x8 af = ldnt(A, pr, 512, kk * 32, lane);
#pragma unroll
    for (int nn = 0; nn < 4; ++nn) {
      f16x8 bf = ldnt(wh, ocq * 64 + nn * 16, 512, kk * 32, lane);
      acc[nn] = mfma16(af, bf, acc[nn]);
    }
  }
  _Float16* O = oT + (size_t)b * N_PIX * 128;
#pragma unroll
  for (int nn = 0; nn < 4; ++nn) {
    int oc = ocq * 64 + nn * 16 + (lane & 15);
    float bb = bias[oc];
#pragma unroll
    for (int r = 0; r < 4; ++r) {
      int pix = pr + ((lane >> 4) << 2) + r;
      O[(size_t)pix * 128 + oc] = (_Float16)(acc[nn][r] + bb);
    }
  }
}

// ---------- one-pass fused attention, producer/consumer, 12 waves, XCD swizzle ----------
// Waves 0-3: QK^T + online softmax. Waves 4-11: K staging + PV (64 c each).
__global__ __launch_bounds__(768, 3) void k_attn(const _Float16* __restrict__ qT, const _Float16* __restrict__ kT,
                                                 const _Float16* __restrict__ vv, const float* __restrict__ x,
                                                 const float* __restrict__ gamma, float* __restrict__ out) {
  __shared__ _Float16 Kb[2][128 * 128];  // 2 x 32KB, row 256B, swizzled by (m&7)<<4
  __shared__ _Float16 P[2][64 * 128];    // 2 x 16KB, row 256B, swizzled by (n&7)<<4
  __shared__ float fbuf[2][64];          // per-n rescale factor, per P buffer
  __shared__ float sbuf[64];             // final sums
  int bid = blockIdx.x;
  int swz = (bid & 7) * 32 + (bid >> 3);
  int n0 = (swz & 63) * 64;
  int b = swz >> 6;
  int tid = threadIdx.x, wid = tid >> 6, lane = tid & 63;
  const _Float16* Q = qT + (size_t)b * N_PIX * 128;
  const _Float16* K = kT + (size_t)b * N_PIX * 128;
  const _Float16* V = vv + (size_t)b * C_IN * N_PIX;
  float g = gamma[0];
  f16x8 qf[4];
  int n_local = (wid & 3) * 16 + (lane & 15);
  if (wid < 4) {
#pragma unroll
    for (int kk = 0; kk < 4; ++kk) qf[kk] = ldnt(Q, n0 + wid * 16, 128, kk * 32, lane);
  }
  float m_run = -3.4e38f, sm = 0.f;
  f32x4 acc[4][4];  // consumer: [cc][nn], 64 VGPR
#pragma unroll
  for (int cc = 0; cc < 4; ++cc)
#pragma unroll
    for (int nn = 0; nn < 4; ++nn) acc[cc][nn] = (f32x4){};

  auto stageK = [&](int it, int buf) {  // waves 4-11 (consumers), 16 rows each
    const _Float16* src = K + (size_t)it * 128 * 128;
    int w8 = wid - 4;
    int cs = (lane & 15) << 4;
#pragma unroll
    for (int i = 0; i < 4; ++i) {
      int rr = w8 * 16 + i * 4 + (lane >> 4);
      const char* gp = (const char*)(src + (size_t)rr * 128) + (cs ^ ((rr & 7) << 4));
      char* lp = (char*)&Kb[buf][0] + (size_t)(w8 * 16 + i * 4) * 256;
      GLOAD_LDS16(gp, lp);
    }
  };

  // producer: S^T for 16 n x 128 m from Kb[it&1], online max/sum, P/fbuf[it&1]
  auto phaseA = [&](int it) {
    int buf = it & 1;
    const char* kb = (const char*)&Kb[buf][0];
    f32x4 s8[8];
#pragma unroll
    for (int mm = 0; mm < 8; ++mm) {
      int row = mm * 16 + (lane & 15);
      int kboff = (lane >> 4) << 4;
      f32x4 s = {};
#pragma unroll
      for (int kk = 0; kk < 4; ++kk) {
        f16x8 kf = *(const f16x8*)(kb + (size_t)row * 256 + ((kk * 64 + kboff) ^ ((row & 7) << 4)));
        s = mfma16(kf, qf[kk], s);  // S^T: col=n, rows=m
      }
      s8[mm] = s;
    }
    float tmx = s8[0][0];
#pragma unroll
    for (int mm = 0; mm < 8; ++mm)
      tmx = fmaxf(tmx, fmaxf(fmaxf(s8[mm][0], s8[mm][1]), fmaxf(s8[mm][2], s8[mm][3])));
    tmx = fmaxf(tmx, __shfl_xor(tmx, 16));
    tmx = fmaxf(tmx, __shfl_xor(tmx, 32));  // per-n slab max
    float f = 1.f;
    if (tmx > m_run + 8.f) {  // defer-max: tolerate P up to e^8
      f = __expf(m_run - tmx);
      m_run = tmx;
    }
    sm *= f;
    if (lane < 16) fbuf[buf][n_local] = f;
#pragma unroll
    for (int mm = 0; mm < 8; ++mm) {
      f16x4 pv;
#pragma unroll
      for (int r = 0; r < 4; ++r) {
        float p = __expf(s8[mm][r] - m_run);
        sm += p;
        pv[r] = (_Float16)p;
      }
      int m_local = mm * 16 + ((lane >> 4) << 2);
      *(f16x4*)((char*)&P[buf][0] + (size_t)n_local * 256 + ((m_local * 2) ^ ((n_local & 7) << 4))) = pv;
    }
  };

  // consumer: PV for 64 c (wid-4) from P[it&1]
  auto phaseB = [&](int it) {
    int buf = it & 1;
    int c0 = (wid - 4) * 64;
    float f[4];
#pragma unroll
    for (int nn = 0; nn < 4; ++nn) f[nn] = fbuf[buf][nn * 16 + (lane & 15)];
    bool need = (f[0] != 1.f) | (f[1] != 1.f) | (f[2] != 1.f) | (f[3] != 1.f);
    if (__any(need)) {
#pragma unroll
      for (int cc = 0; cc < 4; ++cc)
#pragma unroll
        for (int nn = 0; nn < 4; ++nn) acc[cc][nn] = acc[cc][nn] * f[nn];
    }
#pragma unroll
    for (int k2 = 0; k2 < 4; ++k2) {
      f16x8 pb[4];
#pragma unroll
      for (int nn = 0; nn < 4; ++nn) {
        int n = nn * 16 + (lane & 15);
        int mbyte = k2 * 64 + ((lane >> 4) << 4);
        pb[nn] = *(const f16x8*)((char*)&P[buf][0] + (size_t)n * 256 + (mbyte ^ ((n & 7) << 4)));
      }
      __builtin_amdgcn_s_setprio(1);
#pragma unroll
      for (int cc = 0; cc < 4; ++cc) {
        f16x8 af = ldnt(V, c0 + cc * 16, N_PIX, it * 128 + k2 * 32, lane);
#pragma unroll
        for (int nn = 0; nn < 4; ++nn) acc[cc][nn] = mfma16(af, pb[nn], acc[cc][nn]);
      }
      __builtin_amdgcn_s_setprio(0);
    }
  };

  // prologue: consumers stage tiles 0 and 1; producers compute P for tile 0
  if (wid >= 4) {
    stageK(0, 0);
    stageK(1, 1);
  }
  __syncthreads();
  if (wid < 4) phaseA(0);
  __syncthreads();
  // steady state: ONE barrier per iteration
  for (int it = 0; it < 32; ++it) {
    if (wid < 4) {
      if (it < 31) phaseA(it + 1);
    } else {
      if (it < 30) stageK(it + 2, it & 1);  // Kb[it&1] last read in interval it-1
      phaseB(it);
    }
    __syncthreads();
  }

  // epilogue: producers publish per-n total sums; consumers write out
  if (wid < 4) {
    float st = sm;
    st += __shfl_xor(st, 16);
    st += __shfl_xor(st, 32);
    if (lane < 16) sbuf[n_local] = st;
  }
  __syncthreads();
  if (wid >= 4) {
    int c0 = (wid - 4) * 64;
    float inv_s[4];
#pragma unroll
    for (int nn = 0; nn < 4; ++nn) inv_s[nn] = 1.f / sbuf[nn * 16 + (lane & 15)];
#pragma unroll
    for (int cc = 0; cc < 4; ++cc) {
#pragma unroll
      for (int r = 0; r < 4; ++r) {
        int oc = c0 + cc * 16 + ((lane >> 4) << 2) + r;
#pragma unroll
        for (int nn = 0; nn < 4; ++nn) {
          int pix = n0 + nn * 16 + (lane & 15);
          size_t idx = ((size_t)(b * C_IN + oc)) * N_PIX + pix;
          out[idx] = fmaf(g * inv_s[nn], acc[cc][nn][r], x[idx]);
        }
      }
    }
  }
}

extern "C" void kernel_launch(void* const* d_in, const int* in_sizes, int n_in,
                              void* d_out, int out_size, void* d_ws, size_t ws_size,
                              hipStream_t stream) {
  const float* x = (const float*)d_in[0];
  const float* wa1 = (const float*)d_in[1];
  const float* wa2 = (const float*)d_in[2];
  const float* wa3 = (const float*)d_in[3];
  const float* wa4 = (const float*)d_in[4];
  const float* wa5 = (const float*)d_in[5];
  const float* bnS = (const float*)d_in[6];
  const float* bnB = (const float*)d_in[7];
  const float* wq = (const float*)d_in[8];
  const float* bq = (const float*)d_in[9];
  const float* wk = (const float*)d_in[10];
  const float* bk = (const float*)d_in[11];
  const float* wv = (const float*)d_in[12];
  const float* bv = (const float*)d_in[13];
  const float* gamma = (const float*)d_in[14];

  char* ws = (char*)d_ws;
  size_t off = 0;
  auto alloc = [&](size_t bytes) -> char* {
    char* p = ws + off;
    off = (off + bytes + 255) & ~(size_t)255;
    return p;
  };
  _Float16* xT = (_Float16*)alloc((size_t)4 * 4096 * 512 * 2);
  _Float16* featT = (_Float16*)alloc((size_t)4 * 4096 * 512 * 2);
  _Float16* qT = (_Float16*)alloc((size_t)4 * 4096 * 128 * 2);
  _Float16* kT = (_Float16*)alloc((size_t)4 * 4096 * 128 * 2);
  _Float16* vvp = (_Float16*)alloc((size_t)4 * 512 * 4096 * 2);
  _Float16* w1h = (_Float16*)alloc((size_t)128 * 512 * 2);
  _Float16* wph = (_Float16*)alloc((size_t)3 * 9 * 128 * 512 * 2);
  _Float16* wqh = (_Float16*)alloc((size_t)128 * 512 * 2);
  _Float16* wkh = (_Float16*)alloc((size_t)128 * 512 * 2);
  _Float16* wvh = (_Float16*)alloc((size_t)512 * 512 * 2);
  float* meanv = (float*)alloc((size_t)4 * 512 * 4);
  float* bq2 = (float*)alloc((size_t)4 * 128 * 4);
  float* bk2 = (float*)alloc((size_t)4 * 128 * 4);
  if (off > ws_size) return;  // workspace too small -> fail loudly via wrong output

  float* out = (float*)d_out;

  // 1) preprocessing (xT | weight casts | packw | mean)
  hipLaunchKernelGGL(k_pre, dim3(18944), dim3(256), 0, stream, x, xT, wa1, w1h, wv, wvh, wq, wqh, wk, wkh,
                     wa2, wa3, wa4, wph, meanv);
  // 2) conv | v | p5 (co-scheduled)
  hipLaunchKernelGGL(k_mid, dim3(1540), dim3(256), 0, stream, xT, w1h, wph, bnS, bnB, featT, wvh, bv, vvp,
                     wa5, meanv, wq, bq, wk, bk, bq2, bk2);
  // 3) q, k
  hipLaunchKernelGGL(k_qk, dim3(128, 2, 4), dim3(256), 0, stream, featT, wqh, wkh, bq2, bk2, qT, kT);
  // 4) one-pass attention (producer/consumer, 12 waves)
  hipLaunchKernelGGL(k_attn, dim3(256), dim3(768), 0, stream, qT, kT, vvp, x, gamma, out);
}